// Round 17
// baseline (188.464 us; speedup 1.0000x reference)
//
#include <hip/hip_runtime.h>
#include <hip/hip_bf16.h>
#include <cstdint>

typedef __attribute__((ext_vector_type(8))) short bf16x8;
typedef __attribute__((ext_vector_type(4))) float f32x4;
using bf16 = __hip_bfloat16;

static __device__ __forceinline__ void storeval(float* p, float v) { *p = v; }
static __device__ __forceinline__ void storeval(bf16* p, float v) { *p = __float2bfloat16(v); }

#define MFMA_BF16 __builtin_amdgcn_mfma_f32_16x16x32_bf16

template <int N>
static __device__ __forceinline__ void vm_wait() {
    if constexpr (N == 0) asm volatile("s_waitcnt vmcnt(0)" ::: "memory");
    else if constexpr (N == 6) asm volatile("s_waitcnt vmcnt(6)" ::: "memory");
    else if constexpr (N == 8) asm volatile("s_waitcnt vmcnt(8)" ::: "memory");
}
static __device__ __forceinline__ void bar() { __builtin_amdgcn_s_barrier(); }
// pin DS+VMEM at barrier edges; let ALU/VALU/SALU/MFMA flow across
static __device__ __forceinline__ void sb() { __builtin_amdgcn_sched_barrier(0xF); }
static __device__ __forceinline__ void gl_lds(const bf16* src, char* dst) {
    __builtin_amdgcn_global_load_lds((const __attribute__((address_space(1))) unsigned int*)src,
                                     (__attribute__((address_space(3))) unsigned int*)dst, 16, 0, 0);
}

// ================= prep: x->bf16 convert + both weight transposes =================
__global__ __launch_bounds__(256) void prep(const float* __restrict__ x, bf16* __restrict__ xb,
                                            const float* __restrict__ w_qkv, bf16* __restrict__ wqkvT,
                                            const float* __restrict__ w_out, bf16* __restrict__ woutT) {
    __shared__ float tile[32][33];
    const int b = blockIdx.x;
    const int tid = threadIdx.x;
    if (b < 4096) {
        long i = ((long)b * 256 + tid) * 8;
        float4 a = *(const float4*)(x + i);
        float4 c = *(const float4*)(x + i + 4);
        bf16 t[8];
        t[0] = __float2bfloat16(a.x); t[1] = __float2bfloat16(a.y);
        t[2] = __float2bfloat16(a.z); t[3] = __float2bfloat16(a.w);
        t[4] = __float2bfloat16(c.x); t[5] = __float2bfloat16(c.y);
        t[6] = __float2bfloat16(c.z); t[7] = __float2bfloat16(c.w);
        *(uint4*)(xb + i) = *(const uint4*)t;
        return;
    }
    const float* src; bf16* dst; long ss, ds; int tx, ty;
    if (b < 7168) {
        int ib = b - 4096;
        tx = ib % 96; ty = ib / 96;
        src = w_qkv; dst = wqkvT; ss = 3072; ds = 1024;
    } else {
        int ib = b - 7168;
        tx = ib & 31; ty = ib >> 5;
        src = w_out; dst = woutT; ss = 1024; ds = 1024;
    }
    long r0 = (long)ty * 32, c0 = (long)tx * 32;
    int lx = tid & 31, ly = tid >> 5;
    for (int i = ly; i < 32; i += 8)
        tile[i][lx] = src[(r0 + i) * ss + c0 + lx];
    __syncthreads();
    for (int i = ly; i < 32; i += 8)
        dst[(c0 + i) * ds + r0 + lx] = __float2bfloat16(tile[lx][i]);
}

// ======== software-pipelined NT GEMM: C = alpha*A[M,K]*B[N,K]^T (+bias) ========
// BN=256 fixed, BM in {128,256}. BK=64. 8 waves (2M x 4N); per-wave (BM/2)x64.
// 4 phases/K-tile: {bar -> QUAD (operands read >=1 phase earlier) -> next reads}.
// Cyclic operand lifetimes: B(n0) used Q1(P1),Q4(P4) -> refill at P4 AFTER Q4;
// B(n2) used Q2,Q3 -> refill at P1; A(h0) free after P2 -> refill P3; A(h1)
// (aqB) refilled P2. vmcnt(0)@P2 (drains t+1 stages issued 3-4 phases earlier)
// + bar(P3) = all-waves landing guarantee for next-tile reads at P3/P4.
// Stages for t+2: B@P3, A@P4 (WAR-safe: all par reads served before those bars).
// LDS swizzle: 16B granule g of row r at phys g^((r>>1)&7); staging pre-swizzles
// the GLOBAL source. Staging dest = panel + wave*1024 (gl_lds wave-uniform base).
// VSPLIT (QKV only): N-tiles with ntile>=2048 are the V block -> transpose each
// wave's 64t x 64d block through wave-private LDS scratch (main-loop LDS is dead
// after lgkm-drain + barrier), then store vt[z][d][t] in coalesced 32B segments.
template <typename OutT, bool BIAS, int BM, bool VSPLIT>
__global__ __launch_bounds__(512, 1) void gemm_sp(
    const bf16* __restrict__ Ag, long lda, long batchA,
    const bf16* __restrict__ Bg, long ldb, long batchB,
    OutT* __restrict__ Cg, long ldc, long batchC,
    const float* __restrict__ bias, int K, float alpha, int nx, int ny,
    bf16* __restrict__ vtout) {
    constexpr int MR = BM / 32;                      // m-frags per wave: 8 | 4
    constexpr int A_HP = (BM == 256) ? 16384 : 4096; // hp step in RD_A
    constexpr int A_W = (BM == 256) ? 32768 : 16384; // wm step
    constexpr int A_REG = BM * 256;                  // A region bytes = B base
    constexpr int WVP = 4 + BM / 64;                 // prologue wait: tile1 loads
    extern __shared__ __align__(16) char smem[];

    const int tid = threadIdx.x;
    const int wave = tid >> 6, lane = tid & 63, l16 = lane & 15, lhi = lane >> 4;
    const int wm = wave >> 2, wn = wave & 3;

    // XCD-bijective chunked swizzle (nwg % 8 == 0), x-fast inside chunk
    const int nwg = gridDim.x;
    const int l = (blockIdx.x & 7) * (nwg >> 3) + (blockIdx.x >> 3);
    const int pt = nx * ny;
    const int z = l / pt, rr = l % pt;
    const long mtile = (long)(rr / nx) * BM;
    const long ntile = (long)(rr % nx) * 256;

    const bf16* A = Ag + (long)z * batchA;
    const bf16* B = Bg + (long)z * batchB;
    OutT* C = Cg + (long)z * batchC;

    // staging map: row rp0=tid>>3, phys granule tid&7, logical g=(tid&7)^((tid>>4)&7)
    const int rp0 = tid >> 3;
    const int g8 = ((tid & 7) ^ ((tid >> 4) & 7)) * 8;
    const bf16* pA = A + (mtile + rp0) * lda + g8;
    const bf16* pB = B + (ntile + rp0) * ldb + g8;
    const int wb = wave * 1024;

    auto stageB = [&](int par, int t) {  // 4 loads: rows 0-127 then 128-255
        const bf16* s0 = pB + (long)t * 64;
        char* d0 = smem + A_REG + par * 16384 + wb;
        gl_lds(s0, d0);
        gl_lds(s0 + 64 * ldb, d0 + 8192);
        const bf16* s1 = s0 + 128 * ldb;
        char* d1 = smem + A_REG + 32768 + par * 16384 + wb;
        gl_lds(s1, d1);
        gl_lds(s1 + 64 * ldb, d1 + 8192);
    };
    auto stageA = [&](int par, int t) {  // BM/64 loads (64-row quarters)
        const bf16* s0 = pA + (long)t * 64;
#pragma unroll
        for (int q = 0; q < BM / 64; ++q)
            gl_lds(s0 + q * 64 * lda, smem + q * 16384 + par * 8192 + wb);
    };

    // fragment reads: s(row) = (l16>>1)&7
    const int swz = (l16 >> 1) & 7;
    const int cb0 = (lhi ^ swz) * 16;        // k-step 0 granule
    const int cb1 = ((4 + lhi) ^ swz) * 16;  // k-step 1 granule
    const char* aBase = smem + wm * A_W + l16 * 128;
    const char* bBase = smem + A_REG + (wn >> 1) * 32768 + ((wn & 1) * 64 + l16) * 128;

    bf16x8 aqA[MR], aqB[MR], bq[8];
    f32x4 acc[MR][4];
#pragma unroll
    for (int m = 0; m < MR; ++m)
#pragma unroll
        for (int n = 0; n < 4; ++n) acc[m][n] = f32x4{0.f, 0.f, 0.f, 0.f};

#define RD_A(AQ, par, hp)                                                      \
    do {                                                                       \
        const char* p_ = aBase + (par) * 8192 + (hp) * A_HP;                   \
        _Pragma("unroll")                                                      \
        for (int j_ = 0; j_ < MR / 2; ++j_) {                                  \
            AQ[2 * j_]     = *(const bf16x8*)(p_ + j_ * 2048 + cb0);           \
            AQ[2 * j_ + 1] = *(const bf16x8*)(p_ + j_ * 2048 + cb1);           \
        }                                                                      \
    } while (0)

#define RD_B(par, nlo)                                                         \
    do {                                                                       \
        const char* p_ = bBase + (par) * 16384 + (nlo) * 2048;                 \
        bq[(nlo) * 2 + 0] = *(const bf16x8*)(p_ + cb0);                        \
        bq[(nlo) * 2 + 1] = *(const bf16x8*)(p_ + cb1);                        \
        bq[(nlo) * 2 + 2] = *(const bf16x8*)(p_ + 2048 + cb0);                 \
        bq[(nlo) * 2 + 3] = *(const bf16x8*)(p_ + 2048 + cb1);                 \
    } while (0)

// MR MFMAs x 2 n-cols, k-outer (MR independent, then MR at dep distance MR)
#define QUAD_(AQ, h, nlo)                                                      \
    do {                                                                       \
        __builtin_amdgcn_s_setprio(1);                                         \
        _Pragma("unroll")                                                      \
        for (int m_ = 0; m_ < MR / 2; ++m_) {                                  \
            acc[(h) * (MR / 2) + m_][(nlo) + 0] =                              \
                MFMA_BF16(AQ[2*m_], bq[(nlo)*2 + 0], acc[(h)*(MR/2) + m_][(nlo) + 0], 0, 0, 0); \
            acc[(h) * (MR / 2) + m_][(nlo) + 1] =                              \
                MFMA_BF16(AQ[2*m_], bq[(nlo)*2 + 2], acc[(h)*(MR/2) + m_][(nlo) + 1], 0, 0, 0); \
        }                                                                      \
        _Pragma("unroll")                                                      \
        for (int m_ = 0; m_ < MR / 2; ++m_) {                                  \
            acc[(h) * (MR / 2) + m_][(nlo) + 0] =                              \
                MFMA_BF16(AQ[2*m_ + 1], bq[(nlo)*2 + 1], acc[(h)*(MR/2) + m_][(nlo) + 0], 0, 0, 0); \
            acc[(h) * (MR / 2) + m_][(nlo) + 1] =                              \
                MFMA_BF16(AQ[2*m_ + 1], bq[(nlo)*2 + 3], acc[(h)*(MR/2) + m_][(nlo) + 1], 0, 0, 0); \
        }                                                                      \
        __builtin_amdgcn_s_setprio(0);                                         \
    } while (0)

    // MODE 0: stage t+2 + next-tile reads; 1: next-tile reads only; 2: compute only
#define KT(par, tstage, MODE)                                                  \
    do {                                                                       \
        /* P1: Q1 = (A-h0, B-n0) */                                            \
        bar(); sb();                                                           \
        QUAD_(aqA, 0, 0);                                                      \
        RD_B(par, 2);                                                          \
        /* P2: Q2 = (A-h0, B-n2) */                                            \
        bar(); sb();                                                           \
        QUAD_(aqA, 0, 2);                                                      \
        RD_A(aqB, par, 1);                                                     \
        vm_wait<0>();  /* t+1 landed (issued 3-4 phases ago: near-free) */     \
        /* P3: Q3 = (A-h1, B-n2); refill A-h0 for t+1 */                       \
        bar(); sb();   /* all waves waited -> t+1 globally visible */          \
        QUAD_(aqB, 1, 2);                                                      \
        if (MODE < 2) RD_A(aqA, (par) ^ 1, 0);                                 \
        if (MODE == 0) stageB(par, tstage);                                    \
        /* P4: Q4 = (A-h1, B-n0); THEN refill B-n0 for t+1 (bq[0..3] free) */  \
        bar(); sb();                                                           \
        QUAD_(aqB, 1, 0);                                                      \
        if (MODE < 2) RD_B((par) ^ 1, 0);                                      \
        if (MODE == 0) stageA(par, tstage);                                    \
    } while (0)

    const int NT = K / 64;  // even, >= 4

    // prologue: stage tiles 0,1; wait tile0 landed per-wave; bar -> all waves
    stageB(0, 0); stageA(0, 0);
    stageB(1, 1); stageA(1, 1);
    vm_wait<WVP>();
    bar(); sb();
    RD_A(aqA, 0, 0);
    RD_B(0, 0);

    for (int t = 0; t < NT - 2; ++t) KT(t & 1, t + 2, 0);
    KT(0, 0, 1);  // t = NT-2 (par 0): no stages; read tile NT-1 (landed via P2 drain)
    KT(1, 0, 2);  // t = NT-1: compute only

    // epilogue: C/D frag layout col = lane&15, row = (lane>>4)*4 + reg
    if constexpr (VSPLIT) {
        // own-wave LDS reads drained + barrier: main-loop LDS now dead for ALL
        // waves -> safe to reuse as epilogue scratch
        asm volatile("s_waitcnt lgkmcnt(0)" ::: "memory");
        bar();
    }
    if (VSPLIT && ntile >= 2048) {
        // V tile: transpose wave's 64t x 64d block via wave-private LDS scratch,
        // then store vt[z][d][t] rows coalesced (2 lanes per d-row, 4x b128 each).
        constexpr int ST2 = 264;                 // bytes per d-row (132 bf16; 2-way banks)
        char* lws = smem + wave * (32 * ST2);    // 8448 B/wave, 8 waves = 66 KiB
        const long wrow = mtile + wm * 64;       // 64 | 2048: no batch straddle
        const long zz = wrow >> 11;
        const long t0g = wrow & 2047;
        bf16* vbase = vtout + zz * (1024L * 2048);
#pragma unroll
        for (int p = 0; p < 2; ++p) {
            // scatter-write frags for n = 2p, 2p+1 into [dl 0..31][tl 0..63]
#pragma unroll
            for (int nn = 0; nn < 2; ++nn) {
                const int n = 2 * p + nn;
                long col = ntile + wn * 64 + n * 16 + l16;
                float bv = BIAS ? bias[col] : 0.0f;
                const int dl = nn * 16 + l16;
#pragma unroll
                for (int am = 0; am < MR; ++am) {
                    const int h_ = am / (MR / 2), mm = am % (MR / 2);
                    const int tl = h_ * 32 + mm * 16 + lhi * 4;
                    bf16 tmp[4];
#pragma unroll
                    for (int r2 = 0; r2 < 4; ++r2)
                        tmp[r2] = __float2bfloat16(acc[am][n][r2] * alpha + bv);
                    *(uint2*)(lws + dl * ST2 + tl * 2) = *(const uint2*)tmp;
                }
            }
            // gather-read d-rows, store coalesced (in-wave ds ordering suffices:
            // scratch is wave-private; compiler orders aliasing LDS accesses)
            const int dl = lane >> 1;
            const int th = (lane & 1) * 32;
            bf16* dst = vbase + ((ntile - 2048) + wn * 64 + 32 * p + dl) * 2048 + t0g + th;
            const char* srcp = lws + dl * ST2 + th * 2;
#pragma unroll
            for (int i = 0; i < 4; ++i)
                *(uint4*)(dst + i * 8) = *(const uint4*)(srcp + i * 16);
        }
    } else {
#pragma unroll
        for (int n = 0; n < 4; ++n) {
            long col = ntile + wn * 64 + n * 16 + l16;
            float bv = BIAS ? bias[col] : 0.0f;
#pragma unroll
            for (int am = 0; am < MR; ++am) {
                const int h_ = am / (MR / 2), mm = am % (MR / 2);
                long row = mtile + wm * (BM / 2) + h_ * (BM / 4) + mm * 16 + lhi * 4;
#pragma unroll
                for (int r2 = 0; r2 < 4; ++r2)
                    storeval(&C[(row + r2) * ldc + col], acc[am][n][r2] * alpha + bv);
            }
        }
    }
#undef KT
#undef QUAD_
#undef RD_B
#undef RD_A
}

// ---------------- row softmax: bf16 [rows,2048] -> bf16 IN-PLACE ----------------
__global__ __launch_bounds__(256) void softmax_rows_bf16(bf16* __restrict__ S, int ncols) {
    __shared__ float red[8];
    const long row = blockIdx.x;
    bf16* srow = S + row * ncols;
    const int tid = threadIdx.x;
    uint4 raw = *(const uint4*)(srow + tid * 8);
    const bf16* rb = (const bf16*)&raw;
    float v[8];
#pragma unroll
    for (int j = 0; j < 8; ++j) v[j] = __bfloat162float(rb[j]);
    float m = -3.4e38f;
#pragma unroll
    for (int j = 0; j < 8; ++j) m = fmaxf(m, v[j]);
#pragma unroll
    for (int off = 32; off; off >>= 1) m = fmaxf(m, __shfl_xor(m, off));
    if ((tid & 63) == 0) red[tid >> 6] = m;
    __syncthreads();
    m = fmaxf(fmaxf(red[0], red[1]), fmaxf(red[2], red[3]));
    float s = 0.0f;
#pragma unroll
    for (int j = 0; j < 8; ++j) {
        v[j] = __expf(v[j] - m);
        s += v[j];
    }
#pragma unroll
    for (int off = 32; off; off >>= 1) s += __shfl_xor(s, off);
    if ((tid & 63) == 0) red[4 + (tid >> 6)] = s;
    __syncthreads();
    s = red[4] + red[5] + red[6] + red[7];
    float inv = 1.0f / s;
    bf16 o[8];
#pragma unroll
    for (int j = 0; j < 8; ++j) o[j] = __float2bfloat16(v[j] * inv);
    *(uint4*)(srow + tid * 8) = *(const uint4*)o;
}

extern "C" void kernel_launch(void* const* d_in, const int* in_sizes, int n_in, void* d_out,
                              int out_size, void* d_ws, size_t ws_size, hipStream_t stream) {
    (void)in_sizes; (void)n_in; (void)out_size; (void)ws_size;
    const float* x = (const float*)d_in[0];
    const float* w_qkv = (const float*)d_in[1];
    const float* b_qkv = (const float*)d_in[2];
    const float* w_out = (const float*)d_in[3];
    const float* b_out = (const float*)d_in[4];
    float* out = (float*)d_out;

    const int B = 4, S = 2048, D = 1024;

    {
        (void)hipFuncSetAttribute((const void*)&gemm_sp<bf16, true, 128, true>,
                                  hipFuncAttributeMaxDynamicSharedMemorySize, 98304);
        (void)hipFuncSetAttribute((const void*)&gemm_sp<bf16, false, 256, false>,
                                  hipFuncAttributeMaxDynamicSharedMemorySize, 131072);
        (void)hipFuncSetAttribute((const void*)&gemm_sp<bf16, false, 128, false>,
                                  hipFuncAttributeMaxDynamicSharedMemorySize, 98304);
        (void)hipFuncSetAttribute((const void*)&gemm_sp<float, true, 128, false>,
                                  hipFuncAttributeMaxDynamicSharedMemorySize, 98304);
    }

    char* ws = (char*)d_ws;
    size_t off = 0;
    auto alloc = [&](size_t bytes) {
        char* p = ws + off;
        off += (bytes + 255) & ~(size_t)255;
        return p;
    };
    bf16* xb = (bf16*)alloc((size_t)B * S * D * 2);        // 16 MiB
    bf16* qkv = (bf16*)alloc((size_t)B * S * 3 * D * 2);   // 48 MiB (V region unused)
    bf16* wqkvT = (bf16*)alloc((size_t)3 * D * D * 2);     // 6 MiB
    bf16* woutT = (bf16*)alloc((size_t)D * D * 2);         // 2 MiB
    bf16* vt = (bf16*)alloc((size_t)B * D * S * 2);        // 16 MiB
    bf16* ao = (bf16*)alloc((size_t)B * S * D * 2);        // 16 MiB
    bf16* sc = (bf16*)alloc((size_t)B * S * S * 2);        // 33.5 MiB

    // 1. prep: convert x + transpose both weights (one dispatch)
    prep<<<8192, 256, 0, stream>>>(x, xb, w_qkv, wqkvT, w_out, woutT);

    // 2. QKV GEMM: [8192,3072] = xb @ wqkvT^T + b_qkv  (768 blocks = 3 exact rounds)
    //    VSPLIT: Q/K cols -> qkv; V cols transposed straight to vt (LDS-bounce)
    gemm_sp<bf16, true, 128, true><<<768, 512, 98304, stream>>>(
        xb, D, 0, wqkvT, D, 0, qkv, 3 * D, 0, b_qkv, D, 1.0f, 3 * D / 256, B * S / 128, vt);

    // 3. scores = Q K^T / 32, bf16 out (256x256 tiles, 256 blocks = 1 round)
    gemm_sp<bf16, false, 256, false><<<256, 512, 131072, stream>>>(
        qkv, 3 * D, (long)S * 3 * D, qkv + D, 3 * D, (long)S * 3 * D,
        sc, S, (long)S * S, nullptr, D, 0.03125f, S / 256, S / 256, nullptr);

    // 4. softmax in place over bf16 rows
    softmax_rows_bf16<<<B * S, 256, 0, stream>>>(sc, S);

    // 5. ao = attn @ vt^T (128x256 tiles, 256 blocks = 1 round)
    gemm_sp<bf16, false, 128, false><<<256, 512, 98304, stream>>>(
        sc, S, (long)S * S, vt, S, (long)D * S,
        ao, D, (long)S * D, nullptr, S, 1.0f, D / 256, S / 128, nullptr);

    // 6. out proj: out[8192,1024] = ao @ woutT^T + b_out (fp32, 256 blocks)
    gemm_sp<float, true, 128, false><<<256, 512, 98304, stream>>>(
        ao, D, 0, woutT, D, 0, out, D, 0, b_out, D, 1.0f, D / 256, B * S / 128, nullptr);
}

// Round 18
// 186.936 us; speedup vs baseline: 1.0082x; 1.0082x over previous
//
#include <hip/hip_runtime.h>
#include <hip/hip_bf16.h>
#include <cstdint>

typedef __attribute__((ext_vector_type(8))) short bf16x8;
typedef __attribute__((ext_vector_type(4))) float f32x4;
using bf16 = __hip_bfloat16;

static __device__ __forceinline__ void storeval(float* p, float v) { *p = v; }
static __device__ __forceinline__ void storeval(bf16* p, float v) { *p = __float2bfloat16(v); }

#define MFMA_BF16 __builtin_amdgcn_mfma_f32_16x16x32_bf16

template <int N>
static __device__ __forceinline__ void vm_wait() {
    if constexpr (N == 0) asm volatile("s_waitcnt vmcnt(0)" ::: "memory");
    else if constexpr (N == 6) asm volatile("s_waitcnt vmcnt(6)" ::: "memory");
    else if constexpr (N == 8) asm volatile("s_waitcnt vmcnt(8)" ::: "memory");
}
static __device__ __forceinline__ void bar() { __builtin_amdgcn_s_barrier(); }
// pin DS+VMEM at barrier edges; let ALU/VALU/SALU/MFMA flow across
static __device__ __forceinline__ void sb() { __builtin_amdgcn_sched_barrier(0xF); }
static __device__ __forceinline__ void gl_lds(const bf16* src, char* dst) {
    __builtin_amdgcn_global_load_lds((const __attribute__((address_space(1))) unsigned int*)src,
                                     (__attribute__((address_space(3))) unsigned int*)dst, 16, 0, 0);
}

// ================= prep: x->bf16 convert + both weight transposes =================
__global__ __launch_bounds__(256) void prep(const float* __restrict__ x, bf16* __restrict__ xb,
                                            const float* __restrict__ w_qkv, bf16* __restrict__ wqkvT,
                                            const float* __restrict__ w_out, bf16* __restrict__ woutT) {
    __shared__ float tile[32][33];
    const int b = blockIdx.x;
    const int tid = threadIdx.x;
    if (b < 4096) {
        long i = ((long)b * 256 + tid) * 8;
        float4 a = *(const float4*)(x + i);
        float4 c = *(const float4*)(x + i + 4);
        bf16 t[8];
        t[0] = __float2bfloat16(a.x); t[1] = __float2bfloat16(a.y);
        t[2] = __float2bfloat16(a.z); t[3] = __float2bfloat16(a.w);
        t[4] = __float2bfloat16(c.x); t[5] = __float2bfloat16(c.y);
        t[6] = __float2bfloat16(c.z); t[7] = __float2bfloat16(c.w);
        *(uint4*)(xb + i) = *(const uint4*)t;
        return;
    }
    const float* src; bf16* dst; long ss, ds; int tx, ty;
    if (b < 7168) {
        int ib = b - 4096;
        tx = ib % 96; ty = ib / 96;
        src = w_qkv; dst = wqkvT; ss = 3072; ds = 1024;
    } else {
        int ib = b - 7168;
        tx = ib & 31; ty = ib >> 5;
        src = w_out; dst = woutT; ss = 1024; ds = 1024;
    }
    long r0 = (long)ty * 32, c0 = (long)tx * 32;
    int lx = tid & 31, ly = tid >> 5;
    for (int i = ly; i < 32; i += 8)
        tile[i][lx] = src[(r0 + i) * ss + c0 + lx];
    __syncthreads();
    for (int i = ly; i < 32; i += 8)
        dst[(c0 + i) * ds + r0 + lx] = __float2bfloat16(tile[lx][i]);
}

// ======== software-pipelined NT GEMM: C = alpha*A[M,K]*B[N,K]^T (+bias) ========
// BN=256 fixed, BM in {128,256}. BK=64. 8 waves (2M x 4N); per-wave (BM/2)x64.
// 4 phases/K-tile: {bar -> QUAD (operands read >=1 phase earlier) -> next reads}.
// Cyclic operand lifetimes: B(n0) used Q1(P1),Q4(P4) -> refill at P4 AFTER Q4;
// B(n2) used Q2,Q3 -> refill at P1; A(h0) free after P2 -> refill P3; A(h1)
// (aqB) refilled P2. vmcnt(0)@P2 (drains t+1 stages issued 3-4 phases earlier)
// + bar(P3) = all-waves landing guarantee for next-tile reads at P3/P4.
// Stages for t+2: B@P3, A@P4 (WAR-safe: all par reads served before those bars).
// LDS swizzle: 16B granule g of row r at phys g^((r>>1)&7); staging pre-swizzles
// the GLOBAL source. Staging dest = panel + wave*1024 (gl_lds wave-uniform base).
// VSPLIT (QKV only): N-tiles with ntile>=2048 are the V block -> write the
// accumulator TRANSPOSED to vtout[z][col-2048][row] (4 consecutive t-elements
// per lane = one 8B store; tiles never straddle 2048 since 256 | 2048).
template <typename OutT, bool BIAS, int BM, bool VSPLIT>
__global__ __launch_bounds__(512, 1) void gemm_sp(
    const bf16* __restrict__ Ag, long lda, long batchA,
    const bf16* __restrict__ Bg, long ldb, long batchB,
    OutT* __restrict__ Cg, long ldc, long batchC,
    const float* __restrict__ bias, int K, float alpha, int nx, int ny,
    bf16* __restrict__ vtout) {
    constexpr int MR = BM / 32;                      // m-frags per wave: 8 | 4
    constexpr int A_HP = (BM == 256) ? 16384 : 4096; // hp step in RD_A
    constexpr int A_W = (BM == 256) ? 32768 : 16384; // wm step
    constexpr int A_REG = BM * 256;                  // A region bytes = B base
    constexpr int WVP = 4 + BM / 64;                 // prologue wait: tile1 loads
    extern __shared__ __align__(16) char smem[];

    const int tid = threadIdx.x;
    const int wave = tid >> 6, lane = tid & 63, l16 = lane & 15, lhi = lane >> 4;
    const int wm = wave >> 2, wn = wave & 3;

    // XCD-bijective chunked swizzle (nwg % 8 == 0), x-fast inside chunk
    const int nwg = gridDim.x;
    const int l = (blockIdx.x & 7) * (nwg >> 3) + (blockIdx.x >> 3);
    const int pt = nx * ny;
    const int z = l / pt, rr = l % pt;
    const long mtile = (long)(rr / nx) * BM;
    const long ntile = (long)(rr % nx) * 256;

    const bf16* A = Ag + (long)z * batchA;
    const bf16* B = Bg + (long)z * batchB;
    OutT* C = Cg + (long)z * batchC;

    // staging map: row rp0=tid>>3, phys granule tid&7, logical g=(tid&7)^((tid>>4)&7)
    const int rp0 = tid >> 3;
    const int g8 = ((tid & 7) ^ ((tid >> 4) & 7)) * 8;
    const bf16* pA = A + (mtile + rp0) * lda + g8;
    const bf16* pB = B + (ntile + rp0) * ldb + g8;
    const int wb = wave * 1024;

    auto stageB = [&](int par, int t) {  // 4 loads: rows 0-127 then 128-255
        const bf16* s0 = pB + (long)t * 64;
        char* d0 = smem + A_REG + par * 16384 + wb;
        gl_lds(s0, d0);
        gl_lds(s0 + 64 * ldb, d0 + 8192);
        const bf16* s1 = s0 + 128 * ldb;
        char* d1 = smem + A_REG + 32768 + par * 16384 + wb;
        gl_lds(s1, d1);
        gl_lds(s1 + 64 * ldb, d1 + 8192);
    };
    auto stageA = [&](int par, int t) {  // BM/64 loads (64-row quarters)
        const bf16* s0 = pA + (long)t * 64;
#pragma unroll
        for (int q = 0; q < BM / 64; ++q)
            gl_lds(s0 + q * 64 * lda, smem + q * 16384 + par * 8192 + wb);
    };

    // fragment reads: s(row) = (l16>>1)&7
    const int swz = (l16 >> 1) & 7;
    const int cb0 = (lhi ^ swz) * 16;        // k-step 0 granule
    const int cb1 = ((4 + lhi) ^ swz) * 16;  // k-step 1 granule
    const char* aBase = smem + wm * A_W + l16 * 128;
    const char* bBase = smem + A_REG + (wn >> 1) * 32768 + ((wn & 1) * 64 + l16) * 128;

    bf16x8 aqA[MR], aqB[MR], bq[8];
    f32x4 acc[MR][4];
#pragma unroll
    for (int m = 0; m < MR; ++m)
#pragma unroll
        for (int n = 0; n < 4; ++n) acc[m][n] = f32x4{0.f, 0.f, 0.f, 0.f};

#define RD_A(AQ, par, hp)                                                      \
    do {                                                                       \
        const char* p_ = aBase + (par) * 8192 + (hp) * A_HP;                   \
        _Pragma("unroll")                                                      \
        for (int j_ = 0; j_ < MR / 2; ++j_) {                                  \
            AQ[2 * j_]     = *(const bf16x8*)(p_ + j_ * 2048 + cb0);           \
            AQ[2 * j_ + 1] = *(const bf16x8*)(p_ + j_ * 2048 + cb1);           \
        }                                                                      \
    } while (0)

#define RD_B(par, nlo)                                                         \
    do {                                                                       \
        const char* p_ = bBase + (par) * 16384 + (nlo) * 2048;                 \
        bq[(nlo) * 2 + 0] = *(const bf16x8*)(p_ + cb0);                        \
        bq[(nlo) * 2 + 1] = *(const bf16x8*)(p_ + cb1);                        \
        bq[(nlo) * 2 + 2] = *(const bf16x8*)(p_ + 2048 + cb0);                 \
        bq[(nlo) * 2 + 3] = *(const bf16x8*)(p_ + 2048 + cb1);                 \
    } while (0)

// MR MFMAs x 2 n-cols, k-outer (MR independent, then MR at dep distance MR)
#define QUAD_(AQ, h, nlo)                                                      \
    do {                                                                       \
        __builtin_amdgcn_s_setprio(1);                                         \
        _Pragma("unroll")                                                      \
        for (int m_ = 0; m_ < MR / 2; ++m_) {                                  \
            acc[(h) * (MR / 2) + m_][(nlo) + 0] =                              \
                MFMA_BF16(AQ[2*m_], bq[(nlo)*2 + 0], acc[(h)*(MR/2) + m_][(nlo) + 0], 0, 0, 0); \
            acc[(h) * (MR / 2) + m_][(nlo) + 1] =                              \
                MFMA_BF16(AQ[2*m_], bq[(nlo)*2 + 2], acc[(h)*(MR/2) + m_][(nlo) + 1], 0, 0, 0); \
        }                                                                      \
        _Pragma("unroll")                                                      \
        for (int m_ = 0; m_ < MR / 2; ++m_) {                                  \
            acc[(h) * (MR / 2) + m_][(nlo) + 0] =                              \
                MFMA_BF16(AQ[2*m_ + 1], bq[(nlo)*2 + 1], acc[(h)*(MR/2) + m_][(nlo) + 0], 0, 0, 0); \
            acc[(h) * (MR / 2) + m_][(nlo) + 1] =                              \
                MFMA_BF16(AQ[2*m_ + 1], bq[(nlo)*2 + 3], acc[(h)*(MR/2) + m_][(nlo) + 1], 0, 0, 0); \
        }                                                                      \
        __builtin_amdgcn_s_setprio(0);                                         \
    } while (0)

    // MODE 0: stage t+2 + next-tile reads; 1: next-tile reads only; 2: compute only
#define KT(par, tstage, MODE)                                                  \
    do {                                                                       \
        /* P1: Q1 = (A-h0, B-n0) */                                            \
        bar(); sb();                                                           \
        QUAD_(aqA, 0, 0);                                                      \
        RD_B(par, 2);                                                          \
        /* P2: Q2 = (A-h0, B-n2) */                                            \
        bar(); sb();                                                           \
        QUAD_(aqA, 0, 2);                                                      \
        RD_A(aqB, par, 1);                                                     \
        vm_wait<0>();  /* t+1 landed (issued 3-4 phases ago: near-free) */     \
        /* P3: Q3 = (A-h1, B-n2); refill A-h0 for t+1 */                       \
        bar(); sb();   /* all waves waited -> t+1 globally visible */          \
        QUAD_(aqB, 1, 2);                                                      \
        if (MODE < 2) RD_A(aqA, (par) ^ 1, 0);                                 \
        if (MODE == 0) stageB(par, tstage);                                    \
        /* P4: Q4 = (A-h1, B-n0); THEN refill B-n0 for t+1 (bq[0..3] free) */  \
        bar(); sb();                                                           \
        QUAD_(aqB, 1, 0);                                                      \
        if (MODE < 2) RD_B((par) ^ 1, 0);                                      \
        if (MODE == 0) stageA(par, tstage);                                    \
    } while (0)

    const int NT = K / 64;  // even, >= 4

    // prologue: stage tiles 0,1; wait tile0 landed per-wave; bar -> all waves
    stageB(0, 0); stageA(0, 0);
    stageB(1, 1); stageA(1, 1);
    vm_wait<WVP>();
    bar(); sb();
    RD_A(aqA, 0, 0);
    RD_B(0, 0);

    for (int t = 0; t < NT - 2; ++t) KT(t & 1, t + 2, 0);
    KT(0, 0, 1);  // t = NT-2 (par 0): no stages; read tile NT-1 (landed via P2 drain)
    KT(1, 0, 2);  // t = NT-1: compute only

    // epilogue: C/D frag layout col = lane&15, row = (lane>>4)*4 + reg
    if (VSPLIT && ntile >= 2048) {
        // V block: write transposed to vtout[z][col-2048][row]  (z = row>>11;
        // 128-row M-tiles never straddle batches since 128 | 2048)
#pragma unroll
        for (int n = 0; n < 4; ++n) {
            long col = ntile + wn * 64 + n * 16 + l16;
            float bv = BIAS ? bias[col] : 0.0f;
            long d = col - 2048;
#pragma unroll
            for (int am = 0; am < MR; ++am) {
                const int h_ = am / (MR / 2), mm = am % (MR / 2);
                long row = mtile + wm * (BM / 2) + h_ * (BM / 4) + mm * 16 + lhi * 4;
                long zz = row >> 11, s0 = row & 2047;
                bf16 tmp[4];
#pragma unroll
                for (int r2 = 0; r2 < 4; ++r2)
                    tmp[r2] = __float2bfloat16(acc[am][n][r2] * alpha + bv);
                *(uint2*)(vtout + zz * (1024L * 2048) + d * 2048 + s0) = *(const uint2*)tmp;
            }
        }
    } else {
#pragma unroll
        for (int n = 0; n < 4; ++n) {
            long col = ntile + wn * 64 + n * 16 + l16;
            float bv = BIAS ? bias[col] : 0.0f;
#pragma unroll
            for (int am = 0; am < MR; ++am) {
                const int h_ = am / (MR / 2), mm = am % (MR / 2);
                long row = mtile + wm * (BM / 2) + h_ * (BM / 4) + mm * 16 + lhi * 4;
#pragma unroll
                for (int r2 = 0; r2 < 4; ++r2)
                    storeval(&C[(row + r2) * ldc + col], acc[am][n][r2] * alpha + bv);
            }
        }
    }
#undef KT
#undef QUAD_
#undef RD_B
#undef RD_A
}

// ---------------- row softmax: bf16 [rows,2048] -> bf16 IN-PLACE ----------------
__global__ __launch_bounds__(256) void softmax_rows_bf16(bf16* __restrict__ S, int ncols) {
    __shared__ float red[8];
    const long row = blockIdx.x;
    bf16* srow = S + row * ncols;
    const int tid = threadIdx.x;
    uint4 raw = *(const uint4*)(srow + tid * 8);
    const bf16* rb = (const bf16*)&raw;
    float v[8];
#pragma unroll
    for (int j = 0; j < 8; ++j) v[j] = __bfloat162float(rb[j]);
    float m = -3.4e38f;
#pragma unroll
    for (int j = 0; j < 8; ++j) m = fmaxf(m, v[j]);
#pragma unroll
    for (int off = 32; off; off >>= 1) m = fmaxf(m, __shfl_xor(m, off));
    if ((tid & 63) == 0) red[tid >> 6] = m;
    __syncthreads();
    m = fmaxf(fmaxf(red[0], red[1]), fmaxf(red[2], red[3]));
    float s = 0.0f;
#pragma unroll
    for (int j = 0; j < 8; ++j) {
        v[j] = __expf(v[j] - m);
        s += v[j];
    }
#pragma unroll
    for (int off = 32; off; off >>= 1) s += __shfl_xor(s, off);
    if ((tid & 63) == 0) red[4 + (tid >> 6)] = s;
    __syncthreads();
    s = red[4] + red[5] + red[6] + red[7];
    float inv = 1.0f / s;
    bf16 o[8];
#pragma unroll
    for (int j = 0; j < 8; ++j) o[j] = __float2bfloat16(v[j] * inv);
    *(uint4*)(srow + tid * 8) = *(const uint4*)o;
}

extern "C" void kernel_launch(void* const* d_in, const int* in_sizes, int n_in, void* d_out,
                              int out_size, void* d_ws, size_t ws_size, hipStream_t stream) {
    (void)in_sizes; (void)n_in; (void)out_size; (void)ws_size;
    const float* x = (const float*)d_in[0];
    const float* w_qkv = (const float*)d_in[1];
    const float* b_qkv = (const float*)d_in[2];
    const float* w_out = (const float*)d_in[3];
    const float* b_out = (const float*)d_in[4];
    float* out = (float*)d_out;

    const int B = 4, S = 2048, D = 1024;

    {
        (void)hipFuncSetAttribute((const void*)&gemm_sp<bf16, true, 128, true>,
                                  hipFuncAttributeMaxDynamicSharedMemorySize, 98304);
        (void)hipFuncSetAttribute((const void*)&gemm_sp<bf16, false, 256, false>,
                                  hipFuncAttributeMaxDynamicSharedMemorySize, 131072);
        (void)hipFuncSetAttribute((const void*)&gemm_sp<bf16, false, 128, false>,
                                  hipFuncAttributeMaxDynamicSharedMemorySize, 98304);
        (void)hipFuncSetAttribute((const void*)&gemm_sp<float, true, 128, false>,
                                  hipFuncAttributeMaxDynamicSharedMemorySize, 98304);
    }

    char* ws = (char*)d_ws;
    size_t off = 0;
    auto alloc = [&](size_t bytes) {
        char* p = ws + off;
        off += (bytes + 255) & ~(size_t)255;
        return p;
    };
    bf16* xb = (bf16*)alloc((size_t)B * S * D * 2);        // 16 MiB
    bf16* qkv = (bf16*)alloc((size_t)B * S * 3 * D * 2);   // 48 MiB (V region unused)
    bf16* wqkvT = (bf16*)alloc((size_t)3 * D * D * 2);     // 6 MiB
    bf16* woutT = (bf16*)alloc((size_t)D * D * 2);         // 2 MiB
    bf16* vt = (bf16*)alloc((size_t)B * D * S * 2);        // 16 MiB
    bf16* ao = (bf16*)alloc((size_t)B * S * D * 2);        // 16 MiB
    bf16* sc = (bf16*)alloc((size_t)B * S * S * 2);        // 33.5 MiB

    // 1. prep: convert x + transpose both weights (one dispatch)
    prep<<<8192, 256, 0, stream>>>(x, xb, w_qkv, wqkvT, w_out, woutT);

    // 2. QKV GEMM: [8192,3072] = xb @ wqkvT^T + b_qkv  (768 blocks = 3 exact rounds)
    //    VSPLIT: Q/K cols -> qkv; V cols written TRANSPOSED straight to vt
    gemm_sp<bf16, true, 128, true><<<768, 512, 98304, stream>>>(
        xb, D, 0, wqkvT, D, 0, qkv, 3 * D, 0, b_qkv, D, 1.0f, 3 * D / 256, B * S / 128, vt);

    // 3. scores = Q K^T / 32, bf16 out (256x256 tiles, 256 blocks = 1 round)
    gemm_sp<bf16, false, 256, false><<<256, 512, 131072, stream>>>(
        qkv, 3 * D, (long)S * 3 * D, qkv + D, 3 * D, (long)S * 3 * D,
        sc, S, (long)S * S, nullptr, D, 0.03125f, S / 256, S / 256, nullptr);

    // 4. softmax in place over bf16 rows (V-transpose fused into QKV epilogue)
    softmax_rows_bf16<<<B * S, 256, 0, stream>>>(sc, S);

    // 5. ao = attn @ vt^T (128x256 tiles, 256 blocks = 1 round)
    gemm_sp<bf16, false, 128, false><<<256, 512, 98304, stream>>>(
        sc, S, (long)S * S, vt, S, (long)D * S,
        ao, D, (long)S * D, nullptr, S, 1.0f, D / 256, S / 128, nullptr);

    // 6. out proj: out[8192,1024] = ao @ woutT^T + b_out (fp32, 256 blocks)
    gemm_sp<float, true, 128, false><<<256, 512, 98304, stream>>>(
        ao, D, 0, woutT, D, 0, out, D, 0, b_out, D, 1.0f, D / 256, B * S / 128, nullptr);
}